// Round 3
// baseline (2118.836 us; speedup 1.0000x reference)
//
#include <hip/hip_runtime.h>
#include <math.h>

#define BATCH 256
#define CIN 1280
#define COUT 128
#define F1IN 6272
#define F1OUT 4096
#define F2OUT 1470
#define NBOX 98

// ---------------------------------------------------------------------------
// Stage 1: subsample + 1x1 conv.  h1[b, o*49+s] = sum_c x[b,c,2i,2j]*w[o,c]+bias
// Block: one (b, 64-o tile). 256 thr = 16 o-groups x 16 s-groups, 4x4 micro.
// c chunked by 64. s padded to 64 (zero-filled), masked at store.
// ---------------------------------------------------------------------------
__global__ __launch_bounds__(256) void conv_kernel(const float* __restrict__ x,
                                                   const float* __restrict__ w,
                                                   const float* __restrict__ bias,
                                                   double* __restrict__ h1) {
    const int b = blockIdx.x;
    const int obase = blockIdx.y * 64;
    const int tid = threadIdx.x;
    const int to = tid & 15;         // o-group
    const int ts = tid >> 4;         // s-group

    __shared__ float xs[64 * 64];    // [c][s] pitch 64
    __shared__ float wo[64 * 65];    // [o][c] pitch 65

    double acc[4][4];
#pragma unroll
    for (int i = 0; i < 4; ++i)
#pragma unroll
        for (int j = 0; j < 4; ++j) acc[i][j] = 0.0;

    const float* xb = x + (size_t)b * CIN * 196;

    for (int cb = 0; cb < CIN; cb += 64) {
        __syncthreads();
        for (int i = tid; i < 64 * 64; i += 256) {
            int c = i >> 6, s = i & 63;
            float v = 0.0f;
            if (s < 49) {
                int si = s / 7, sj = s - si * 7;
                v = xb[(size_t)(cb + c) * 196 + si * 28 + sj * 2];
            }
            xs[c * 64 + s] = v;
        }
        for (int i = tid; i < 64 * 64; i += 256) {
            int o = i >> 6, c = i & 63;
            wo[o * 65 + c] = w[(size_t)(obase + o) * CIN + cb + c];
        }
        __syncthreads();
        for (int c = 0; c < 64; ++c) {
            float xv[4], wv[4];
#pragma unroll
            for (int q = 0; q < 4; ++q) xv[q] = xs[c * 64 + ts * 4 + q];
#pragma unroll
            for (int q = 0; q < 4; ++q) wv[q] = wo[(to * 4 + q) * 65 + c];
            double xd[4], wd[4];
#pragma unroll
            for (int q = 0; q < 4; ++q) { xd[q] = (double)xv[q]; wd[q] = (double)wv[q]; }
#pragma unroll
            for (int i = 0; i < 4; ++i)
#pragma unroll
                for (int j = 0; j < 4; ++j)
                    acc[i][j] = fma(wd[i], xd[j], acc[i][j]);
        }
    }

#pragma unroll
    for (int i = 0; i < 4; ++i) {
        int o = obase + to * 4 + i;
        double bv = (double)bias[o];
#pragma unroll
        for (int j = 0; j < 4; ++j) {
            int s = ts * 4 + j;
            if (s < 49)
                h1[(size_t)b * F1IN + (size_t)o * 49 + s] = acc[i][j] + bv;
        }
    }
}

// ---------------------------------------------------------------------------
// FC GEMM split-K (NT): partial C[m][n] += sum_{k slice} A[m][k]*W[n][k]
// A: double MxK row-major, W: float NxK row-major. C pre-zeroed; fp64 atomicAdd.
// 128x128 tile, K-chunk 16, 256 threads, 8x8 micro, kk-major padded LDS.
// ---------------------------------------------------------------------------
template <bool NCHECK>
__global__ __launch_bounds__(256, 2) void fc_splitk_kernel(const double* __restrict__ A,
                                                           const float* __restrict__ W,
                                                           double* __restrict__ C,
                                                           int N, int K, int kchunks) {
    __shared__ double As[16 * 130];   // [kk][m], pitch 130 (16B-aligned rows)
    __shared__ float  Ws[16 * 132];   // [kk][n], pitch 132 (16B-aligned rows)

    const int mbase = blockIdx.x * 128;
    const int nbase = blockIdx.y * 128;
    const int kb0 = blockIdx.z * kchunks * 16;
    const int kb1 = kb0 + kchunks * 16;
    const int tid = threadIdx.x;
    const int tm = tid >> 4;   // 0..15
    const int tn = tid & 15;   // 0..15

    double acc[8][8];
#pragma unroll
    for (int i = 0; i < 8; ++i)
#pragma unroll
        for (int j = 0; j < 8; ++j) acc[i][j] = 0.0;

    for (int kb = kb0; kb < kb1; kb += 16) {
        __syncthreads();
        for (int i = tid; i < 2048; i += 256) {
            int r = i >> 4, kk = i & 15;
            As[kk * 130 + r] = A[(size_t)(mbase + r) * K + kb + kk];
        }
        for (int i = tid; i < 2048; i += 256) {
            int r = i >> 4, kk = i & 15;
            int n = nbase + r;
            Ws[kk * 132 + r] = (!NCHECK || n < N) ? W[(size_t)n * K + kb + kk] : 0.0f;
        }
        __syncthreads();
#pragma unroll 4
        for (int kk = 0; kk < 16; ++kk) {
            double a[8], bd[8];
#pragma unroll
            for (int i = 0; i < 8; ++i) a[i] = As[kk * 130 + tm * 8 + i];
#pragma unroll
            for (int j = 0; j < 8; ++j) bd[j] = (double)Ws[kk * 132 + tn * 8 + j];
#pragma unroll
            for (int i = 0; i < 8; ++i)
#pragma unroll
                for (int j = 0; j < 8; ++j)
                    acc[i][j] = fma(a[i], bd[j], acc[i][j]);
        }
    }

#pragma unroll
    for (int i = 0; i < 8; ++i) {
        int m = mbase + tm * 8 + i;
#pragma unroll
        for (int j = 0; j < 8; ++j) {
            int n = nbase + tn * 8 + j;
            if (!NCHECK || n < N)
                atomicAdd(&C[(size_t)m * N + n], acc[i][j]);
        }
    }
}

// epilogue: C += bias, optional leaky relu
template <bool LEAKY>
__global__ __launch_bounds__(256) void bias_act_kernel(double* __restrict__ C,
                                                       const float* __restrict__ bias,
                                                       int N, size_t total) {
    size_t idx = (size_t)blockIdx.x * 256 + threadIdx.x;
    if (idx >= total) return;
    int n = (int)(idx % (size_t)N);
    double v = C[idx] + (double)bias[n];
    if (LEAKY) v = (v >= 0.0) ? v : 0.1 * v;
    C[idx] = v;
}

// ---------------------------------------------------------------------------
// Stage 4: sigmoid + decode + stable sort + greedy NMS + top-10. One block / image.
// ---------------------------------------------------------------------------
__global__ __launch_bounds__(128) void decode_nms_kernel(const double* __restrict__ Z,
                                                         float* __restrict__ out_boxes,
                                                         float* __restrict__ out_labels,
                                                         float* __restrict__ out_confs) {
    const int b = blockIdx.x;
    const int tid = threadIdx.x;

    __shared__ double sAll[F2OUT];
    __shared__ double bx[NBOX][4];
    __shared__ double cf[NBOX];
    __shared__ int lab[NBOX];
    __shared__ double sbx[NBOX][4];
    __shared__ double scf[NBOX];
    __shared__ int slab[NBOX];
    __shared__ unsigned long long suprow[NBOX][2];

    const double* z = Z + (size_t)b * F2OUT;
    for (int i = tid; i < F2OUT; i += 128)
        sAll[i] = 1.0 / (1.0 + exp(-z[i]));
    __syncthreads();

    for (int n = tid; n < NBOX; n += 128) {
        int gi = n / 14;
        int gj = (n % 14) >> 1;
        double cx = sAll[4 * n + 0] * 64.0 + 64.0 * (double)gi;
        double cy = sAll[4 * n + 1] * 64.0 + 64.0 * (double)gj;
        double w  = sAll[4 * n + 2] * 448.0;
        double hh = sAll[4 * n + 3] * 448.0;
        double x1 = cx - 0.5 * w,  y1 = cy - 0.5 * hh;
        double x2 = cx + 0.5 * w,  y2 = cy + 0.5 * hh;
        x1 = x1 < 0.0 ? 0.0 : (x1 > 448.0 ? 448.0 : x1);
        y1 = y1 < 0.0 ? 0.0 : (y1 > 448.0 ? 448.0 : y1);
        x2 = x2 < 0.0 ? 0.0 : (x2 > 448.0 ? 448.0 : x2);
        y2 = y2 < 0.0 ? 0.0 : (y2 > 448.0 ? 448.0 : y2);
        bx[n][0] = x1; bx[n][1] = y1; bx[n][2] = x2; bx[n][3] = y2;
        cf[n] = sAll[392 + n];
        int cell = n >> 1;
        double best = sAll[490 + cell * 20];
        int bl = 0;
        for (int c = 1; c < 20; ++c) {
            double v = sAll[490 + cell * 20 + c];
            if (v > best) { best = v; bl = c; }
        }
        lab[n] = bl;
    }
    __syncthreads();

    for (int n = tid; n < NBOX; n += 128) {
        double cn = cf[n];
        int r = 0;
        for (int m = 0; m < NBOX; ++m) {
            double cm = cf[m];
            if (cm > cn || (cm == cn && m < n)) ++r;
        }
        scf[r] = cn;
        slab[r] = lab[n];
        sbx[r][0] = bx[n][0]; sbx[r][1] = bx[n][1];
        sbx[r][2] = bx[n][2]; sbx[r][3] = bx[n][3];
    }
    __syncthreads();

    for (int i = tid; i < NBOX; i += 128) {
        double x1 = sbx[i][0], y1 = sbx[i][1], x2 = sbx[i][2], y2 = sbx[i][3];
        double ai = fmax(x2 - x1, 0.0) * fmax(y2 - y1, 0.0);
        unsigned long long m0 = 0ull, m1 = 0ull;
        for (int j = 0; j < NBOX; ++j) {
            double jx1 = sbx[j][0], jy1 = sbx[j][1], jx2 = sbx[j][2], jy2 = sbx[j][3];
            double xx1 = fmax(x1, jx1), yy1 = fmax(y1, jy1);
            double xx2 = fmin(x2, jx2), yy2 = fmin(y2, jy2);
            double inter = fmax(xx2 - xx1, 0.0) * fmax(yy2 - yy1, 0.0);
            double aj = fmax(jx2 - jx1, 0.0) * fmax(jy2 - jy1, 0.0);
            double uni = ai + aj - inter;
            double iou = (uni > 0.0) ? inter / uni : 0.0;
            if (iou > 0.7) {
                if (j < 64) m0 |= 1ull << j;
                else        m1 |= 1ull << (j - 64);
            }
        }
        suprow[i][0] = m0;
        suprow[i][1] = m1;
    }
    __syncthreads();

    if (tid == 0) {
        unsigned long long k0 = 0ull, k1 = 0ull;
        for (int i = 0; i < NBOX; ++i) {
            if (scf[i] > 0.1) {
                if (i < 64) k0 |= 1ull << i;
                else        k1 |= 1ull << (i - 64);
            }
        }
        for (int i = 0; i < NBOX; ++i) {
            bool ki = (i < 64) ? ((k0 >> i) & 1ull) : ((k1 >> (i - 64)) & 1ull);
            if (!ki) continue;
            unsigned long long g0, g1;
            if (i < 63)       { g0 = (~0ull) << (i + 1); g1 = ~0ull; }
            else if (i == 63) { g0 = 0ull;               g1 = ~0ull; }
            else              { g0 = 0ull;               g1 = (~0ull) << (i - 63); }
            k0 &= ~(suprow[i][0] & g0);
            k1 &= ~(suprow[i][1] & g1);
        }
        int cnt = 0;
        for (int i = 0; i < NBOX && cnt < 10; ++i) {
            bool ki = (i < 64) ? ((k0 >> i) & 1ull) : ((k1 >> (i - 64)) & 1ull);
            if (!ki) continue;
            out_boxes[(size_t)b * 40 + cnt * 4 + 0] = (float)sbx[i][0];
            out_boxes[(size_t)b * 40 + cnt * 4 + 1] = (float)sbx[i][1];
            out_boxes[(size_t)b * 40 + cnt * 4 + 2] = (float)sbx[i][2];
            out_boxes[(size_t)b * 40 + cnt * 4 + 3] = (float)sbx[i][3];
            out_labels[b * 10 + cnt] = (float)slab[i];
            out_confs[b * 10 + cnt]  = (float)scf[i];
            ++cnt;
        }
        for (; cnt < 10; ++cnt) {
            out_boxes[(size_t)b * 40 + cnt * 4 + 0] = 0.0f;
            out_boxes[(size_t)b * 40 + cnt * 4 + 1] = 0.0f;
            out_boxes[(size_t)b * 40 + cnt * 4 + 2] = 0.0f;
            out_boxes[(size_t)b * 40 + cnt * 4 + 3] = 0.0f;
            out_labels[b * 10 + cnt] = 0.0f;
            out_confs[b * 10 + cnt]  = 0.0f;
        }
    }
}

extern "C" void kernel_launch(void* const* d_in, const int* in_sizes, int n_in,
                              void* d_out, int out_size, void* d_ws, size_t ws_size,
                              hipStream_t stream) {
    const float* x      = (const float*)d_in[0];
    const float* conv_w = (const float*)d_in[1];
    const float* conv_b = (const float*)d_in[2];
    const float* fc1_w  = (const float*)d_in[3];
    const float* fc1_b  = (const float*)d_in[4];
    const float* fc2_w  = (const float*)d_in[5];
    const float* fc2_b  = (const float*)d_in[6];

    double* h1 = (double*)d_ws;                       // 256 x 6272
    double* a1 = h1 + (size_t)BATCH * F1IN;           // 256 x 4096
    double* a2 = a1 + (size_t)BATCH * F1OUT;          // 256 x 1470

    float* out_boxes  = (float*)d_out;                // 256*10*4
    float* out_labels = out_boxes + (size_t)BATCH * 40;   // 256*10
    float* out_confs  = out_labels + (size_t)BATCH * 10;  // 256*10

    hipMemsetAsync(a1, 0, (size_t)BATCH * F1OUT * sizeof(double), stream);
    hipMemsetAsync(a2, 0, (size_t)BATCH * F2OUT * sizeof(double), stream);

    conv_kernel<<<dim3(BATCH, 2), 256, 0, stream>>>(x, conv_w, conv_b, h1);

    // FC1: M=256,N=4096,K=6272. Tiles 128x128, k-split 8 (49 chunks each) = 512 blocks.
    fc_splitk_kernel<false><<<dim3(2, 32, 8), 256, 0, stream>>>(h1, fc1_w, a1, F1OUT, F1IN, 49);
    {
        size_t total = (size_t)BATCH * F1OUT;
        bias_act_kernel<true><<<(int)((total + 255) / 256), 256, 0, stream>>>(a1, fc1_b, F1OUT, total);
    }

    // FC2: M=256,N=1470,K=4096. Tiles 128x128, k-split 32 (8 chunks each) = 768 blocks.
    fc_splitk_kernel<true><<<dim3(2, 12, 32), 256, 0, stream>>>(a1, fc2_w, a2, F2OUT, F1OUT, 8);
    {
        size_t total = (size_t)BATCH * F2OUT;
        bias_act_kernel<false><<<(int)((total + 255) / 256), 256, 0, stream>>>(a2, fc2_b, F2OUT, total);
    }

    decode_nms_kernel<<<BATCH, 128, 0, stream>>>(a2, out_boxes, out_labels, out_confs);
}